// Round 6
// baseline (266.007 us; speedup 1.0000x reference)
//
#include <hip/hip_runtime.h>
#include <hip/hip_bf16.h>
#include <cstdint>
#include <cstddef>

// LSTMCell: gates = [input|hx] @ [Wih|Whh]^T + b_ih + b_hh  (4096 x 4096 x K=2048)
// Round 6: f16 split-A 2-product GEMM (absmax 0.047 verified R5).
// Occupancy fix: 128x32h tile, BK=32, 24 KB LDS -> grid 1024 = 4 blocks/CU,
// 16 waves/CU. Same proven 2-barrier m97 loop + k-chunk-panel LDS layout.

#define B_ROWS 4096
#define HDIM   1024
#define KDIM   2048
#define BM     128
#define H_BLK  32
#define BK     32
#define T_STEPS (KDIM / BK)   // 64

typedef unsigned short u16;
using f32x4  = __attribute__((ext_vector_type(4))) float;
using short8 = __attribute__((ext_vector_type(8))) short;
using half8  = __attribute__((ext_vector_type(8))) _Float16;

__device__ __forceinline__ u16 f2h_bits(float f) {
    _Float16 h = (_Float16)f;                    // v_cvt_f16_f32, RTN
    return __builtin_bit_cast(u16, h);
}
__device__ __forceinline__ float h2f(u16 s) {
    return (float)__builtin_bit_cast(_Float16, s);
}

// ---------------- pack: f32 -> f16 (A split hi/lo, W single), concat K-dim ----------------
__global__ void pack_kernel(const float* __restrict__ input, const float* __restrict__ hx,
                            const float* __restrict__ wih, const float* __restrict__ whh,
                            u16* __restrict__ Ah, u16* __restrict__ Al,
                            u16* __restrict__ Wf)
{
    const int PER = (B_ROWS * KDIM) / 4;  // float4 groups per matrix
    int stride = gridDim.x * blockDim.x;
    for (int i = blockIdx.x * blockDim.x + threadIdx.x; i < 2 * PER; i += stride) {
        int isW = (i >= PER) ? 1 : 0;
        int e = i - isW * PER;
        int row = e >> 9;            // 512 float4-groups per row of 2048
        int k = (e & 511) << 2;
        const float* s0 = isW ? wih : input;
        const float* s1 = isW ? whh : hx;
        const float* src = (k < 1024) ? (s0 + (size_t)row * 1024 + k)
                                      : (s1 + (size_t)row * 1024 + (k - 1024));
        float4 v = *(const float4*)src;
        size_t doff = (size_t)row * KDIM + k;
        if (isW) {
            *(ushort4*)(Wf + doff) = make_ushort4(f2h_bits(v.x), f2h_bits(v.y),
                                                  f2h_bits(v.z), f2h_bits(v.w));
        } else {
            u16 h0 = f2h_bits(v.x), h1 = f2h_bits(v.y), h2 = f2h_bits(v.z), h3 = f2h_bits(v.w);
            *(ushort4*)(Ah + doff) = make_ushort4(h0, h1, h2, h3);
            *(ushort4*)(Al + doff) = make_ushort4(f2h_bits(v.x - h2f(h0)),
                                                  f2h_bits(v.y - h2f(h1)),
                                                  f2h_bits(v.z - h2f(h2)),
                                                  f2h_bits(v.w - h2f(h3)));
        }
    }
}

// ---------------- fused GEMM + LSTM epilogue ----------------
__device__ __forceinline__ void gload16(const void* g, void* l) {
    __builtin_amdgcn_global_load_lds((const __attribute__((address_space(1))) void*)g,
                                     (__attribute__((address_space(3))) void*)l, 16, 0, 0);
}
__device__ __forceinline__ float sigmf(float x) { return 1.0f / (1.0f + __expf(-x)); }
__device__ __forceinline__ float tanhfast(float x) { return 1.0f - 2.0f / (1.0f + __expf(2.0f * x)); }

__launch_bounds__(256, 4)
__global__ void lstm_fused(const u16* __restrict__ Ahp, const u16* __restrict__ Alp,
                           const u16* __restrict__ Wfp,
                           const float* __restrict__ cx, const float* __restrict__ eps_c,
                           const float* __restrict__ eps_h,
                           const float* __restrict__ bias_ih, const float* __restrict__ bias_hh,
                           const float* __restrict__ noise_q, const float* __restrict__ noise_e,
                           float* __restrict__ out)
{
    // k-chunk-panel layout: [kc(4)][row][8] u16 — linear for global_load_lds,
    // conflict-free ds_read_b128 (0 conflicts measured R1-R5). 8+8+8 = 24 KB.
    __shared__ __align__(16) u16 lAh[4][BM][8];
    __shared__ __align__(16) u16 lAl[4][BM][8];
    __shared__ __align__(16) u16 lW [4][128][8];

    const int nwg = 1024;
    int bid = blockIdx.x;
    // XCD-bijective swizzle (1024 % 8 == 0): XCD x gets 4 consecutive hq values
    // (W working set 4 x 0.5 MB = 2 MB, L2-resident) x all 32 A panels.
    int w = (bid & 7) * (nwg >> 3) + (bid >> 3);
    int mi = w & 31;          // 32 M-chunks of 128 rows
    int hq = w >> 5;          // 32 h-chunks of 32 cols
    int bm0 = mi * BM;
    int h0 = hq * H_BLK;

    int tid  = threadIdx.x;
    int lane = tid & 63;
    int wv   = tid >> 6;      // wave id 0..3
    int wm   = wv & 1;        // M half (64 rows)
    int wn   = wv >> 1;       // h half (16 cols)

    // ---- staging mappings ----
    // A: thread -> row = tid&127, half p = tid>>7; covers (tensor,kc) combos c = p+2s
    int rA = tid & 127;
    int pA = tid >> 7;        // 0/1
    const u16* Asrc_h = Ahp + (size_t)(bm0 + rA) * KDIM;
    const u16* Asrc_l = Alp + (size_t)(bm0 + rA) * KDIM;
    // W: thread -> LDS row rW = tid&127, kc sweeps {p, p+2}
    // LDS W row n <-> global gate row: gate = n>>5, h = h0 + (n&31)
    int rW = tid & 127;
    int wgrow = (rW >> 5) * 1024 + h0 + (rW & 31);
    const u16* Wsrc = Wfp + (size_t)wgrow * KDIM;

    // ---- fragment read indices ----
    int fk = lane >> 4, fr = lane & 15;

    f32x4 acc[4][4];   // [m-frag][gate]
#pragma unroll
    for (int m = 0; m < 4; ++m)
#pragma unroll
        for (int g = 0; g < 4; ++g)
            acc[m][g] = (f32x4){0.f, 0.f, 0.f, 0.f};

#pragma unroll 1
    for (int kt = 0; kt < T_STEPS; ++kt) {
        int kk = kt * BK;
        // ---- stage 24 KB: 6 x global_load_lds_dwordx4 per thread ----
#pragma unroll
        for (int s = 0; s < 4; ++s) {
            int c = pA + 2 * s;          // 0..7 across the two thread halves
            int tensor = c >> 2, kc = c & 3;
            if (tensor == 0) gload16(Asrc_h + kk + kc * 8, &lAh[kc][rA][0]);
            else             gload16(Asrc_l + kk + kc * 8, &lAl[kc][rA][0]);
        }
#pragma unroll
        for (int s = 0; s < 2; ++s) {
            int kc = pA + 2 * s;
            gload16(Wsrc + kk + kc * 8, &lW[kc][rW][0]);
        }
        __syncthreads();   // drains vmcnt before barrier

        half8 ah[4], al[4], wf[4];
#pragma unroll
        for (int m = 0; m < 4; ++m) {
            ah[m] = __builtin_bit_cast(half8, *(const short8*)&lAh[fk][wm * 64 + m * 16 + fr][0]);
            al[m] = __builtin_bit_cast(half8, *(const short8*)&lAl[fk][wm * 64 + m * 16 + fr][0]);
        }
#pragma unroll
        for (int g = 0; g < 4; ++g)
            wf[g] = __builtin_bit_cast(half8, *(const short8*)&lW[fk][g * 32 + wn * 16 + fr][0]);

        // hi products (acc reuse distance 16), then lo products
#pragma unroll
        for (int g = 0; g < 4; ++g)
#pragma unroll
            for (int m = 0; m < 4; ++m)
                acc[m][g] = __builtin_amdgcn_mfma_f32_16x16x32_f16(ah[m], wf[g], acc[m][g], 0, 0, 0);
#pragma unroll
        for (int g = 0; g < 4; ++g)
#pragma unroll
            for (int m = 0; m < 4; ++m)
                acc[m][g] = __builtin_amdgcn_mfma_f32_16x16x32_f16(al[m], wf[g], acc[m][g], 0, 0, 0);
        __syncthreads();
    }

    // ---- epilogue: all 4 gates for (r,h) are lane-local ----
    float sq_e = sqrtf(noise_e[0]);
    float sq_q = sqrtf(noise_q[0]);
    int h = h0 + wn * 16 + fr;
    float bsum[4];
#pragma unroll
    for (int g = 0; g < 4; ++g)
        bsum[g] = bias_ih[g * 1024 + h] + bias_hh[g * 1024 + h];
#pragma unroll
    for (int m = 0; m < 4; ++m) {
        int r0 = bm0 + wm * 64 + m * 16 + fk * 4;
#pragma unroll
        for (int j = 0; j < 4; ++j) {
            int r = r0 + j;
            float gi = acc[m][0][j] + bsum[0];
            float gf = acc[m][1][j] + bsum[1];
            float gc = acc[m][2][j] + bsum[2];
            float go = acc[m][3][j] + bsum[3];
            float ig = sigmf(gi), fg = sigmf(gf);
            float cg = tanhfast(gc), og = sigmf(go);
            size_t off = (size_t)r * HDIM + h;
            float cyv = fg * cx[off] + ig * cg + sq_e * eps_c[off];
            float hyv = og * tanhfast(cyv) + sq_q * eps_h[off];
            out[off] = hyv;                                 // hy
            out[(size_t)B_ROWS * HDIM + off] = cyv;         // cy
        }
    }
}

extern "C" void kernel_launch(void* const* d_in, const int* in_sizes, int n_in,
                              void* d_out, int out_size, void* d_ws, size_t ws_size,
                              hipStream_t stream)
{
    const float* input = (const float*)d_in[0];
    const float* hx    = (const float*)d_in[1];
    const float* cx    = (const float*)d_in[2];
    const float* nq    = (const float*)d_in[3];
    const float* ne    = (const float*)d_in[4];
    const float* wih   = (const float*)d_in[5];
    const float* whh   = (const float*)d_in[6];
    const float* bih   = (const float*)d_in[7];
    const float* bhh   = (const float*)d_in[8];
    const float* epsc  = (const float*)d_in[9];
    const float* epsh  = (const float*)d_in[10];
    float* out = (float*)d_out;

    u16* Ah = (u16*)d_ws;
    u16* Al = Ah + (size_t)B_ROWS * KDIM;
    u16* Wf = Al + (size_t)B_ROWS * KDIM;   // 48 MB of ws total

    hipLaunchKernelGGL(pack_kernel, dim3(2048), dim3(256), 0, stream,
                       input, hx, wih, whh, Ah, Al, Wf);
    hipLaunchKernelGGL(lstm_fused, dim3(1024), dim3(256), 0, stream,
                       Ah, Al, Wf, cx, epsc, epsh, bih, bhh, nq, ne, out);
}

// Round 7
// 173.331 us; speedup vs baseline: 1.5347x; 1.5347x over previous
//
#include <hip/hip_runtime.h>
#include <hip/hip_bf16.h>
#include <cstdint>
#include <cstddef>

// LSTMCell: gates = [input|hx] @ [Wih|Whh]^T + b_ih + b_hh  (4096 x 4096 x K=2048)
// Round 7: f16 split-A 2-product GEMM (absmax 0.047 verified R5) on the verified
// m201 8-phase schedule: 256x256 tile, 8 waves, BK=32, 3-sub-buffer ring (144 KB),
// per-phase {ds_read || stage} -> barrier -> lgkmcnt(0) -> setprio -> 16 MFMA,
// counted vmcnt(6) once per K-step (never 0 in steady state), prefetch distance 2.

#define B_ROWS 4096
#define HDIM   1024
#define KDIM   2048
#define BM     256
#define BK     32
#define T_STEPS (KDIM / BK)   // 64

typedef unsigned short u16;
using f32x4  = __attribute__((ext_vector_type(4))) float;
using short8 = __attribute__((ext_vector_type(8))) short;
using half8  = __attribute__((ext_vector_type(8))) _Float16;

__device__ __forceinline__ u16 f2h_bits(float f) {
    _Float16 h = (_Float16)f;                    // v_cvt_f16_f32, RTN
    return __builtin_bit_cast(u16, h);
}
__device__ __forceinline__ float h2f(u16 s) {
    return (float)__builtin_bit_cast(_Float16, s);
}

// ---------------- pack: f32 -> f16 (A split hi/lo, W single), concat K-dim ----------------
__global__ void pack_kernel(const float* __restrict__ input, const float* __restrict__ hx,
                            const float* __restrict__ wih, const float* __restrict__ whh,
                            u16* __restrict__ Ah, u16* __restrict__ Al,
                            u16* __restrict__ Wf)
{
    const int PER = (B_ROWS * KDIM) / 4;  // float4 groups per matrix
    int stride = gridDim.x * blockDim.x;
    for (int i = blockIdx.x * blockDim.x + threadIdx.x; i < 2 * PER; i += stride) {
        int isW = (i >= PER) ? 1 : 0;
        int e = i - isW * PER;
        int row = e >> 9;            // 512 float4-groups per row of 2048
        int k = (e & 511) << 2;
        const float* s0 = isW ? wih : input;
        const float* s1 = isW ? whh : hx;
        const float* src = (k < 1024) ? (s0 + (size_t)row * 1024 + k)
                                      : (s1 + (size_t)row * 1024 + (k - 1024));
        float4 v = *(const float4*)src;
        size_t doff = (size_t)row * KDIM + k;
        if (isW) {
            *(ushort4*)(Wf + doff) = make_ushort4(f2h_bits(v.x), f2h_bits(v.y),
                                                  f2h_bits(v.z), f2h_bits(v.w));
        } else {
            u16 h0 = f2h_bits(v.x), h1 = f2h_bits(v.y), h2 = f2h_bits(v.z), h3 = f2h_bits(v.w);
            *(ushort4*)(Ah + doff) = make_ushort4(h0, h1, h2, h3);
            *(ushort4*)(Al + doff) = make_ushort4(f2h_bits(v.x - h2f(h0)),
                                                  f2h_bits(v.y - h2f(h1)),
                                                  f2h_bits(v.z - h2f(h2)),
                                                  f2h_bits(v.w - h2f(h3)));
        }
    }
}

// ---------------- fused GEMM + LSTM epilogue ----------------
__device__ __forceinline__ void gload16(const void* g, void* l) {
    __builtin_amdgcn_global_load_lds((const __attribute__((address_space(1))) void*)g,
                                     (__attribute__((address_space(3))) void*)l, 16, 0, 0);
}
__device__ __forceinline__ float sigmf(float x) { return 1.0f / (1.0f + __expf(-x)); }
__device__ __forceinline__ float tanhfast(float x) { return 1.0f - 2.0f / (1.0f + __expf(2.0f * x)); }

__launch_bounds__(512, 2)
__global__ void lstm_fused(const u16* __restrict__ Ahp, const u16* __restrict__ Alp,
                           const u16* __restrict__ Wfp,
                           const float* __restrict__ cx, const float* __restrict__ eps_c,
                           const float* __restrict__ eps_h,
                           const float* __restrict__ bias_ih, const float* __restrict__ bias_hh,
                           const float* __restrict__ noise_q, const float* __restrict__ noise_e,
                           float* __restrict__ out)
{
    // k-chunk-panel layout [sb(3)][kc(4)][row(256)][8] u16 — linear for global_load_lds,
    // conflict-free ds_read_b128 (0 conflicts measured R1-R6). 3 x 16 KB x 3 tiles = 144 KB.
    __shared__ __align__(16) u16 lAh[3][4][256][8];
    __shared__ __align__(16) u16 lAl[3][4][256][8];
    __shared__ __align__(16) u16 lW [3][4][256][8];

    int bid = blockIdx.x;
    // XCD-bijective swizzle (256 % 8 == 0): XCD x gets w in [32x,32x+32) -> 2 hq
    // values (W working set 2 MB, L2-resident) x all 16 A panels.
    int w = (bid & 7) * 32 + (bid >> 3);
    int mi = w & 15;          // 16 M-chunks of 256 rows
    int hq = w >> 4;          // 16 h-chunks of 64 cols (x4 gates = 256 gate-cols)
    int bm0 = mi * BM;
    int h0 = hq * 64;

    int tid  = threadIdx.x;
    int lane = tid & 63;
    int wid  = tid >> 6;      // 0..7
    int wm   = wid >> 2;      // M half (128 rows)
    int wn   = wid & 3;       // h quarter (16 cols x 4 gates = 64 gate-cols)

    // ---- staging mapping: thread -> (row = tid&255, kc base = tid>>8), 2 loads kc,kc+2 ----
    int rSt = tid & 255;
    int kS  = tid >> 8;       // 0/1
    const u16* Asrc_h = Ahp + (size_t)(bm0 + rSt) * KDIM;
    const u16* Asrc_l = Alp + (size_t)(bm0 + rSt) * KDIM;
    // LDS W row n <-> global gate row: gate = n>>6, h = h0 + (n&63)
    int wgrow = (rSt >> 6) * 1024 + h0 + (rSt & 63);
    const u16* Wsrc = Wfp + (size_t)wgrow * KDIM;

#define STG_AH(sb, t_) do { \
        gload16(Asrc_h + (t_) * 32 + kS * 8,       &lAh[sb][kS][rSt][0]);     \
        gload16(Asrc_h + (t_) * 32 + (kS + 2) * 8, &lAh[sb][kS + 2][rSt][0]); } while (0)
#define STG_AL(sb, t_) do { \
        gload16(Asrc_l + (t_) * 32 + kS * 8,       &lAl[sb][kS][rSt][0]);     \
        gload16(Asrc_l + (t_) * 32 + (kS + 2) * 8, &lAl[sb][kS + 2][rSt][0]); } while (0)
#define STG_W(sb, t_) do { \
        gload16(Wsrc + (t_) * 32 + kS * 8,         &lW[sb][kS][rSt][0]);      \
        gload16(Wsrc + (t_) * 32 + (kS + 2) * 8,   &lW[sb][kS + 2][rSt][0]);  } while (0)

    // ---- fragment read indices ----
    int fk = lane >> 4, fr = lane & 15;

    f32x4 acc[8][4];   // [m-frag][gate]
#pragma unroll
    for (int m = 0; m < 8; ++m)
#pragma unroll
        for (int g = 0; g < 4; ++g)
            acc[m][g] = (f32x4){0.f, 0.f, 0.f, 0.f};

    // ---- prologue: stage steps 0,1 into sb0,sb1; wait only sb0 (6 newest in flight) ----
    STG_AH(0, 0); STG_AL(0, 0); STG_W(0, 0);
    STG_AH(1, 1); STG_AL(1, 1); STG_W(1, 1);
    asm volatile("s_waitcnt vmcnt(6)");
    __builtin_amdgcn_s_barrier();

#define LD8(p) __builtin_bit_cast(half8, *(const short8*)(p))

#define PH_MFMA(mb, AH0, AH1, AL0, AL1) do { \
        __builtin_amdgcn_s_setprio(1); \
        _Pragma("unroll") \
        for (int g = 0; g < 4; ++g) { \
            acc[(mb)][g]     = __builtin_amdgcn_mfma_f32_16x16x32_f16(AH0, wf[g], acc[(mb)][g], 0, 0, 0); \
            acc[(mb) + 1][g] = __builtin_amdgcn_mfma_f32_16x16x32_f16(AH1, wf[g], acc[(mb) + 1][g], 0, 0, 0); \
        } \
        _Pragma("unroll") \
        for (int g = 0; g < 4; ++g) { \
            acc[(mb)][g]     = __builtin_amdgcn_mfma_f32_16x16x32_f16(AL0, wf[g], acc[(mb)][g], 0, 0, 0); \
            acc[(mb) + 1][g] = __builtin_amdgcn_mfma_f32_16x16x32_f16(AL1, wf[g], acc[(mb) + 1][g], 0, 0, 0); \
        } \
        __builtin_amdgcn_s_setprio(0); \
    } while (0)

#define WAIT_LGKM() do { \
        asm volatile("s_waitcnt lgkmcnt(0)"); \
        __builtin_amdgcn_sched_barrier(0); \
    } while (0)

#pragma unroll 1
    for (int t = 0; t < T_STEPS; ++t) {
        int scur = t % 3;
        int spre = (t + 2) % 3;
        bool pre = (t < T_STEPS - 2);
        const u16* pAh = &lAh[scur][fk][wm * 128 + fr][0];
        const u16* pAl = &lAl[scur][fk][wm * 128 + fr][0];
        const u16* pW  = &lW [scur][fk][wn * 16 + fr][0];

        half8 wf[4];
        half8 a0, a1, b0, b1, c0, c1, d0, d1;

        // ---- Phase A: W frags + A m0,m1 ; stage Ah(t+2) ----
#pragma unroll
        for (int g = 0; g < 4; ++g) wf[g] = LD8(pW + g * 512);
        a0 = LD8(pAh);       a1 = LD8(pAh + 128);
        b0 = LD8(pAl);       b1 = LD8(pAl + 128);
        if (pre) STG_AH(spre, t + 2);
        __builtin_amdgcn_s_barrier();
        WAIT_LGKM();
        PH_MFMA(0, a0, a1, b0, b1);
        __builtin_amdgcn_s_barrier();

        // ---- Phase B: A m2,m3 ; stage Al(t+2) ----
        c0 = LD8(pAh + 2 * 128); c1 = LD8(pAh + 3 * 128);
        d0 = LD8(pAl + 2 * 128); d1 = LD8(pAl + 3 * 128);
        if (pre) STG_AL(spre, t + 2);
        __builtin_amdgcn_s_barrier();
        WAIT_LGKM();
        PH_MFMA(2, c0, c1, d0, d1);
        __builtin_amdgcn_s_barrier();

        // ---- Phase C: A m4,m5 ; stage W(t+2) ----
        a0 = LD8(pAh + 4 * 128); a1 = LD8(pAh + 5 * 128);
        b0 = LD8(pAl + 4 * 128); b1 = LD8(pAl + 5 * 128);
        if (pre) STG_W(spre, t + 2);
        __builtin_amdgcn_s_barrier();
        WAIT_LGKM();
        PH_MFMA(4, a0, a1, b0, b1);
        __builtin_amdgcn_s_barrier();

        // ---- Phase D: A m6,m7 ; counted vmcnt (t+1's loads done, t+2's in flight) ----
        c0 = LD8(pAh + 6 * 128); c1 = LD8(pAh + 7 * 128);
        d0 = LD8(pAl + 6 * 128); d1 = LD8(pAl + 7 * 128);
        __builtin_amdgcn_s_barrier();
        WAIT_LGKM();
        PH_MFMA(6, c0, c1, d0, d1);
        if (pre) asm volatile("s_waitcnt vmcnt(6)");
        else     asm volatile("s_waitcnt vmcnt(0)");
        __builtin_amdgcn_s_barrier();
        __builtin_amdgcn_sched_barrier(0);   // pin: nothing crosses the step boundary
    }

    // ---- epilogue: all 4 gates for (r,h) are lane-local ----
    float sq_e = sqrtf(noise_e[0]);
    float sq_q = sqrtf(noise_q[0]);
    int h = h0 + wn * 16 + fr;
    float bsum[4];
#pragma unroll
    for (int g = 0; g < 4; ++g)
        bsum[g] = bias_ih[g * 1024 + h] + bias_hh[g * 1024 + h];
#pragma unroll
    for (int m = 0; m < 8; ++m) {
        int r0 = bm0 + wm * 128 + m * 16 + fk * 4;
#pragma unroll
        for (int j = 0; j < 4; ++j) {
            int r = r0 + j;
            float gi = acc[m][0][j] + bsum[0];
            float gf = acc[m][1][j] + bsum[1];
            float gc = acc[m][2][j] + bsum[2];
            float go = acc[m][3][j] + bsum[3];
            float ig = sigmf(gi), fg = sigmf(gf);
            float cg = tanhfast(gc), og = sigmf(go);
            size_t off = (size_t)r * HDIM + h;
            float cyv = fg * cx[off] + ig * cg + sq_e * eps_c[off];
            float hyv = og * tanhfast(cyv) + sq_q * eps_h[off];
            out[off] = hyv;                                 // hy
            out[(size_t)B_ROWS * HDIM + off] = cyv;         // cy
        }
    }
}

extern "C" void kernel_launch(void* const* d_in, const int* in_sizes, int n_in,
                              void* d_out, int out_size, void* d_ws, size_t ws_size,
                              hipStream_t stream)
{
    const float* input = (const float*)d_in[0];
    const float* hx    = (const float*)d_in[1];
    const float* cx    = (const float*)d_in[2];
    const float* nq    = (const float*)d_in[3];
    const float* ne    = (const float*)d_in[4];
    const float* wih   = (const float*)d_in[5];
    const float* whh   = (const float*)d_in[6];
    const float* bih   = (const float*)d_in[7];
    const float* bhh   = (const float*)d_in[8];
    const float* epsc  = (const float*)d_in[9];
    const float* epsh  = (const float*)d_in[10];
    float* out = (float*)d_out;

    u16* Ah = (u16*)d_ws;
    u16* Al = Ah + (size_t)B_ROWS * KDIM;
    u16* Wf = Al + (size_t)B_ROWS * KDIM;   // 48 MB of ws total

    hipLaunchKernelGGL(pack_kernel, dim3(2048), dim3(256), 0, stream,
                       input, hx, wih, whh, Ah, Al, Wf);
    hipLaunchKernelGGL(lstm_fused, dim3(256), dim3(512), 0, stream,
                       Ah, Al, Wf, cx, epsc, epsh, bih, bhh, nq, ne, out);
}

// Round 8
// 113.398 us; speedup vs baseline: 2.3458x; 1.5285x over previous
//
#include <hip/hip_runtime.h>
#include <hip/hip_bf16.h>
#include <cstdint>
#include <cstddef>

// LSTMCell: gates = [input|hx] @ [Wih|Whh]^T + b_ih + b_hh  (4096 x 4096 x K=2048)
// Round 8: SINGLE-product f16 GEMM (A,W both f16; sigma_gate ~4.5e-3, predicted
// absmax ~0.06-0.08 < 0.13). 69 GFLOP. R7's verified phase protocol: 256x256 tile,
// 8 waves, BK=32, 3-sub-buffer ring, 2 phases/step {ds_read || stage -> barrier ->
// lgkmcnt(0) -> setprio 16 MFMA}, counted vmcnt(4) (never 0 in steady state).

#define B_ROWS 4096
#define HDIM   1024
#define KDIM   2048
#define BM     256
#define BK     32
#define T_STEPS (KDIM / BK)   // 64

typedef unsigned short u16;
using f32x4  = __attribute__((ext_vector_type(4))) float;
using short8 = __attribute__((ext_vector_type(8))) short;
using half8  = __attribute__((ext_vector_type(8))) _Float16;

__device__ __forceinline__ u16 f2h_bits(float f) {
    _Float16 h = (_Float16)f;                    // v_cvt_f16_f32, RTN
    return __builtin_bit_cast(u16, h);
}

// ---------------- pack: f32 -> f16, concat K-dim ----------------
__global__ void pack_kernel(const float* __restrict__ input, const float* __restrict__ hx,
                            const float* __restrict__ wih, const float* __restrict__ whh,
                            u16* __restrict__ Af, u16* __restrict__ Wf)
{
    const int PER = (B_ROWS * KDIM) / 4;  // float4 groups per matrix
    int stride = gridDim.x * blockDim.x;
    for (int i = blockIdx.x * blockDim.x + threadIdx.x; i < 2 * PER; i += stride) {
        int isW = (i >= PER) ? 1 : 0;
        int e = i - isW * PER;
        int row = e >> 9;            // 512 float4-groups per row of 2048
        int k = (e & 511) << 2;
        const float* s0 = isW ? wih : input;
        const float* s1 = isW ? whh : hx;
        const float* src = (k < 1024) ? (s0 + (size_t)row * 1024 + k)
                                      : (s1 + (size_t)row * 1024 + (k - 1024));
        float4 v = *(const float4*)src;
        size_t doff = (size_t)row * KDIM + k;
        u16* dst = (isW ? Wf : Af) + doff;
        *(ushort4*)dst = make_ushort4(f2h_bits(v.x), f2h_bits(v.y),
                                      f2h_bits(v.z), f2h_bits(v.w));
    }
}

// ---------------- fused GEMM + LSTM epilogue ----------------
__device__ __forceinline__ void gload16(const void* g, void* l) {
    __builtin_amdgcn_global_load_lds((const __attribute__((address_space(1))) void*)g,
                                     (__attribute__((address_space(3))) void*)l, 16, 0, 0);
}
__device__ __forceinline__ float sigmf(float x) { return 1.0f / (1.0f + __expf(-x)); }
__device__ __forceinline__ float tanhfast(float x) { return 1.0f - 2.0f / (1.0f + __expf(2.0f * x)); }

__launch_bounds__(512, 2)
__global__ void lstm_fused(const u16* __restrict__ Afp, const u16* __restrict__ Wfp,
                           const float* __restrict__ cx, const float* __restrict__ eps_c,
                           const float* __restrict__ eps_h,
                           const float* __restrict__ bias_ih, const float* __restrict__ bias_hh,
                           const float* __restrict__ noise_q, const float* __restrict__ noise_e,
                           float* __restrict__ out)
{
    // k-chunk-panel layout [sb(3)][kc(4)][row(256)][8] u16 — linear for global_load_lds,
    // conflict-free ds_read_b128 (0 conflicts measured R1-R7). 3 x 16 KB x 2 tiles = 96 KB.
    __shared__ __align__(16) u16 lA[3][4][256][8];
    __shared__ __align__(16) u16 lW[3][4][256][8];

    int bid = blockIdx.x;
    // XCD-bijective swizzle (256 % 8 == 0): XCD x gets w in [32x,32x+32) -> 2 hq
    // values (W working set 2 MB, L2-resident) x all 16 A panels.
    int w = (bid & 7) * 32 + (bid >> 3);
    int mi = w & 15;          // 16 M-chunks of 256 rows
    int hq = w >> 4;          // 16 h-chunks of 64 cols (x4 gates = 256 gate-cols)
    int bm0 = mi * BM;
    int h0 = hq * 64;

    int tid  = threadIdx.x;
    int lane = tid & 63;
    int wid  = tid >> 6;      // 0..7
    int wm   = wid >> 2;      // M half (128 rows)
    int wn   = wid & 3;       // h quarter (16 cols x 4 gates = 64 gate-cols)

    // ---- staging mapping: thread -> (row = tid&255, kc base = tid>>8), 2 loads kc,kc+2 ----
    int rSt = tid & 255;
    int kS  = tid >> 8;       // 0/1
    const u16* Asrc = Afp + (size_t)(bm0 + rSt) * KDIM;
    // LDS W row n <-> global gate row: gate = n>>6, h = h0 + (n&63)
    int wgrow = (rSt >> 6) * 1024 + h0 + (rSt & 63);
    const u16* Wsrc = Wfp + (size_t)wgrow * KDIM;

#define STG_A(sb, t_) do { \
        gload16(Asrc + (t_) * 32 + kS * 8,       &lA[sb][kS][rSt][0]);     \
        gload16(Asrc + (t_) * 32 + (kS + 2) * 8, &lA[sb][kS + 2][rSt][0]); } while (0)
#define STG_W(sb, t_) do { \
        gload16(Wsrc + (t_) * 32 + kS * 8,       &lW[sb][kS][rSt][0]);     \
        gload16(Wsrc + (t_) * 32 + (kS + 2) * 8, &lW[sb][kS + 2][rSt][0]); } while (0)

    // ---- fragment read indices ----
    int fk = lane >> 4, fr = lane & 15;

    f32x4 acc[8][4];   // [m-frag][gate]
#pragma unroll
    for (int m = 0; m < 8; ++m)
#pragma unroll
        for (int g = 0; g < 4; ++g)
            acc[m][g] = (f32x4){0.f, 0.f, 0.f, 0.f};

    // ---- prologue: stage steps 0,1 into sb0,sb1; wait only sb0 (4 newest in flight) ----
    STG_A(0, 0); STG_W(0, 0);
    STG_A(1, 1); STG_W(1, 1);
    asm volatile("s_waitcnt vmcnt(4)");
    __builtin_amdgcn_s_barrier();

#define LD8(p) __builtin_bit_cast(half8, *(const short8*)(p))

#define PH_MFMA(mb, A0, A1, A2, A3) do { \
        __builtin_amdgcn_s_setprio(1); \
        _Pragma("unroll") \
        for (int g = 0; g < 4; ++g) { \
            acc[(mb)][g]     = __builtin_amdgcn_mfma_f32_16x16x32_f16(A0, wf[g], acc[(mb)][g], 0, 0, 0); \
            acc[(mb) + 1][g] = __builtin_amdgcn_mfma_f32_16x16x32_f16(A1, wf[g], acc[(mb) + 1][g], 0, 0, 0); \
        } \
        _Pragma("unroll") \
        for (int g = 0; g < 4; ++g) { \
            acc[(mb) + 2][g] = __builtin_amdgcn_mfma_f32_16x16x32_f16(A2, wf[g], acc[(mb) + 2][g], 0, 0, 0); \
            acc[(mb) + 3][g] = __builtin_amdgcn_mfma_f32_16x16x32_f16(A3, wf[g], acc[(mb) + 3][g], 0, 0, 0); \
        } \
        __builtin_amdgcn_s_setprio(0); \
    } while (0)

#define WAIT_LGKM() do { \
        asm volatile("s_waitcnt lgkmcnt(0)"); \
        __builtin_amdgcn_sched_barrier(0); \
    } while (0)

#pragma unroll 1
    for (int t = 0; t < T_STEPS; ++t) {
        int scur = t % 3;
        int spre = (t + 2) % 3;
        bool pre = (t < T_STEPS - 2);
        const u16* pA = &lA[scur][fk][wm * 128 + fr][0];
        const u16* pW = &lW[scur][fk][wn * 16 + fr][0];

        half8 wf[4];
        half8 a0, a1, a2, a3, b0, b1, b2, b3;

        // ---- Phase A: W frags + A m0..m3 ; stage A(t+2) ----
#pragma unroll
        for (int g = 0; g < 4; ++g) wf[g] = LD8(pW + g * 512);
        a0 = LD8(pA);           a1 = LD8(pA + 128);
        a2 = LD8(pA + 2 * 128); a3 = LD8(pA + 3 * 128);
        if (pre) STG_A(spre, t + 2);
        __builtin_amdgcn_s_barrier();
        WAIT_LGKM();
        PH_MFMA(0, a0, a1, a2, a3);
        __builtin_amdgcn_s_barrier();

        // ---- Phase B: A m4..m7 ; stage W(t+2) ; counted vmcnt ----
        b0 = LD8(pA + 4 * 128); b1 = LD8(pA + 5 * 128);
        b2 = LD8(pA + 6 * 128); b3 = LD8(pA + 7 * 128);
        if (pre) STG_W(spre, t + 2);
        __builtin_amdgcn_s_barrier();
        WAIT_LGKM();
        PH_MFMA(4, b0, b1, b2, b3);
        if (pre) asm volatile("s_waitcnt vmcnt(4)");   // t+1's loads done; t+2's in flight
        else     asm volatile("s_waitcnt vmcnt(0)");
        __builtin_amdgcn_s_barrier();
        __builtin_amdgcn_sched_barrier(0);   // pin: nothing crosses the step boundary
    }

    // ---- epilogue: all 4 gates for (r,h) are lane-local ----
    float sq_e = sqrtf(noise_e[0]);
    float sq_q = sqrtf(noise_q[0]);
    int h = h0 + wn * 16 + fr;
    float bsum[4];
#pragma unroll
    for (int g = 0; g < 4; ++g)
        bsum[g] = bias_ih[g * 1024 + h] + bias_hh[g * 1024 + h];
#pragma unroll
    for (int m = 0; m < 8; ++m) {
        int r0 = bm0 + wm * 128 + m * 16 + fk * 4;
#pragma unroll
        for (int j = 0; j < 4; ++j) {
            int r = r0 + j;
            float gi = acc[m][0][j] + bsum[0];
            float gf = acc[m][1][j] + bsum[1];
            float gc = acc[m][2][j] + bsum[2];
            float go = acc[m][3][j] + bsum[3];
            float ig = sigmf(gi), fg = sigmf(gf);
            float cg = tanhfast(gc), og = sigmf(go);
            size_t off = (size_t)r * HDIM + h;
            float cyv = fg * cx[off] + ig * cg + sq_e * eps_c[off];
            float hyv = og * tanhfast(cyv) + sq_q * eps_h[off];
            out[off] = hyv;                                 // hy
            out[(size_t)B_ROWS * HDIM + off] = cyv;         // cy
        }
    }
}

extern "C" void kernel_launch(void* const* d_in, const int* in_sizes, int n_in,
                              void* d_out, int out_size, void* d_ws, size_t ws_size,
                              hipStream_t stream)
{
    const float* input = (const float*)d_in[0];
    const float* hx    = (const float*)d_in[1];
    const float* cx    = (const float*)d_in[2];
    const float* nq    = (const float*)d_in[3];
    const float* ne    = (const float*)d_in[4];
    const float* wih   = (const float*)d_in[5];
    const float* whh   = (const float*)d_in[6];
    const float* bih   = (const float*)d_in[7];
    const float* bhh   = (const float*)d_in[8];
    const float* epsc  = (const float*)d_in[9];
    const float* epsh  = (const float*)d_in[10];
    float* out = (float*)d_out;

    u16* Af = (u16*)d_ws;
    u16* Wf = Af + (size_t)B_ROWS * KDIM;   // 32 MB of ws total

    hipLaunchKernelGGL(pack_kernel, dim3(2048), dim3(256), 0, stream,
                       input, hx, wih, whh, Af, Wf);
    hipLaunchKernelGGL(lstm_fused, dim3(256), dim3(512), 0, stream,
                       Af, Wf, cx, epsc, epsh, bih, bhh, nq, ne, out);
}